// Round 5
// baseline (17.552 us; speedup 1.0000x reference)
//
#include <hip/hip_runtime.h>
#include <math.h>

#define BB 8
#define TM1 127

typedef _Float16 f16x4 __attribute__((ext_vector_type(4)));
typedef float f32x4 __attribute__((ext_vector_type(4)));
typedef unsigned int u32x4 __attribute__((ext_vector_type(4)));

__device__ __forceinline__ float lrelu(float v) { return v > 0.0f ? v : 0.01f * v; }

__global__ __launch_bounds__(256, 4) void gat_kernel(
    const float* __restrict__ x,       // (8,64,128,8)
    const float* __restrict__ W_sp,    // (24,64)
    const float* __restrict__ b_sp,    // (64)
    const float* __restrict__ W_node,  // (8,64)
    const float* __restrict__ b_node,  // (64)
    const float* __restrict__ W_att,   // (64,1)
    const float* __restrict__ b_att,   // (1)
    float* __restrict__ out)           // (8,127,64,64)
{
    const int bt = blockIdx.x;
    const int b = bt / TM1;
    const int t = bt - b * TM1;
    const int tid = threadIdx.x;
    const int lane = tid & 63;
    const int wid = tid >> 6;

    __shared__ __align__(16) float x2[2][64][8];            // 4 KB
    __shared__ __align__(16) unsigned short Nh[64][72];     // 9 KB (f16 ne, [d][f], 144B rows)
    __shared__ __align__(16) float u_sh[64];
    __shared__ __align__(16) float w_sh[64];

    // ---- phase 0: stage x_t, x_{t+1}; ALL waves redundantly allreduce p,q,c0,c1 ----
    {
        int n = tid >> 2;
        int sel = tid & 3;
        int tile = sel >> 1, half = sel & 1;
        const float* src = x + (((long)(b * 64 + n) * 128) + (t + tile)) * 8 + half * 4;
        *(float4*)&x2[tile][n][half * 4] = *(const float4*)src;
    }
    float Wn[8];
#pragma unroll
    for (int k = 0; k < 8; ++k) Wn[k] = W_node[k * 64 + lane];
    const float bnode_d = b_node[lane];
    const float batt = b_att[0];

    float pv[8], qv[8], c0, c1;
    {
        float wa = W_att[lane];
        float vals[18];
#pragma unroll
        for (int k = 0; k < 8; ++k) vals[k] = Wn[k] * wa;
#pragma unroll
        for (int k = 0; k < 8; ++k)
            vals[8 + k] = (W_sp[(8 + k) * 64 + lane] + W_sp[(16 + k) * 64 + lane]) * wa;
        vals[16] = b_sp[lane] * wa;
        vals[17] = bnode_d * wa;
#pragma unroll
        for (int i = 0; i < 18; ++i) {
            float v = vals[i];
#pragma unroll
            for (int off = 32; off > 0; off >>= 1) v += __shfl_xor(v, off, 64);
            vals[i] = v;  // butterfly allreduce: every lane has the sum
        }
#pragma unroll
        for (int k = 0; k < 8; ++k) { pv[k] = vals[k]; qv[k] = vals[8 + k]; }
        c0 = vals[16]; c1 = vals[17];
    }
    __syncthreads();

    // ---- phase 1a: u[n], w[n] ----
    if (tid < 64) {
        f32x4 a0 = *(const f32x4*)&x2[0][tid][0];
        f32x4 a1 = *(const f32x4*)&x2[0][tid][4];
        f32x4 d0 = *(const f32x4*)&x2[1][tid][0];
        f32x4 d1 = *(const f32x4*)&x2[1][tid][4];
        float su = 0.f, sw = 0.f;
#pragma unroll
        for (int e = 0; e < 4; ++e) {
            su += a0[e] * pv[e] + a1[e] * pv[4 + e];
            sw += (d0[e] - a0[e]) * qv[e] + (d1[e] - a1[e]) * qv[4 + e];
        }
        u_sh[tid] = su + c1;
        w_sh[tid] = sw + c0;
    }

    // ---- phase 1b: ne[f][d] = x_t@W_node + b ; f16, write [d][f] ----
    {
        unsigned int hw[8];
#pragma unroll
        for (int p = 0; p < 8; ++p) {
            float acc0 = bnode_d, acc1 = bnode_d;
            int f0 = wid * 16 + 2 * p;
            f32x4 xa = *(const f32x4*)&x2[0][f0][0];
            f32x4 xb = *(const f32x4*)&x2[0][f0][4];
            f32x4 ya = *(const f32x4*)&x2[0][f0 + 1][0];
            f32x4 yb = *(const f32x4*)&x2[0][f0 + 1][4];
#pragma unroll
            for (int e = 0; e < 4; ++e) {
                acc0 += xa[e] * Wn[e] + xb[e] * Wn[4 + e];
                acc1 += ya[e] * Wn[e] + yb[e] * Wn[4 + e];
            }
            _Float16 h0 = (_Float16)acc0, h1 = (_Float16)acc1;
            hw[p] = (unsigned int)__builtin_bit_cast(unsigned short, h0) |
                    ((unsigned int)__builtin_bit_cast(unsigned short, h1) << 16);
        }
        u32x4 qa = {hw[0], hw[1], hw[2], hw[3]};
        u32x4 qb = {hw[4], hw[5], hw[6], hw[7]};
        *(u32x4*)&Nh[lane][wid * 16]     = qa;
        *(u32x4*)&Nh[lane][wid * 16 + 8] = qb;
    }
    __syncthreads();

    // ---- phase 2: S + softmax in registers (A-frag layout), MFMA, store ----
    {
        const int i = lane & 15;
        const int g4 = (lane >> 4) * 4;
        const int n = wid * 16 + i;          // this lane's attention row
        const float un = u_sh[n];

        float a[16];
#pragma unroll
        for (int s4 = 0; s4 < 4; ++s4) {
            f32x4 uf = *(const f32x4*)&u_sh[s4 * 16 + g4];
            f32x4 wf = *(const f32x4*)&w_sh[s4 * 16 + g4];
#pragma unroll
            for (int e = 0; e < 4; ++e) {
                int f = s4 * 16 + g4 + e;
                float v = lrelu(un + uf[e] + wf[e] + batt);
                a[s4 * 4 + e] = (f == n) ? 0.0f : v;
            }
        }
        // row softmax: row n lives in lanes {i, i+16, i+32, i+48}
        float m = a[0];
#pragma unroll
        for (int j = 1; j < 16; ++j) m = fmaxf(m, a[j]);
        m = fmaxf(m, __shfl_xor(m, 16, 64));
        m = fmaxf(m, __shfl_xor(m, 32, 64));
        float s = 0.f;
#pragma unroll
        for (int j = 0; j < 16; ++j) {
            float e = __expf(a[j] - m);
            a[j] = e;
            s += e;
        }
        s += __shfl_xor(s, 16, 64);
        s += __shfl_xor(s, 32, 64);
        const float inv = 1.0f / s;

        f16x4 Ah[4];
#pragma unroll
        for (int s4 = 0; s4 < 4; ++s4)
#pragma unroll
            for (int e = 0; e < 4; ++e)
                Ah[s4][e] = (_Float16)(a[s4 * 4 + e] * inv);

        f32x4 acc[4];
#pragma unroll
        for (int c = 0; c < 4; ++c) acc[c] = (f32x4){0.f, 0.f, 0.f, 0.f};

#pragma unroll
        for (int c = 0; c < 4; ++c) {
            const int col = c * 16 + i;
#pragma unroll
            for (int s4 = 0; s4 < 4; ++s4) {
                f16x4 bh = *(const f16x4*)&Nh[col][s4 * 16 + g4];
                acc[c] = __builtin_amdgcn_mfma_f32_16x16x16f16(Ah[s4], bh, acc[c], 0, 0, 0);
            }
        }

        float* op = out + ((long)(b * TM1 + t) << 12);
#pragma unroll
        for (int c = 0; c < 4; ++c) {
#pragma unroll
            for (int r = 0; r < 4; ++r) {
                int row = wid * 16 + g4 + r;     // C/D: row = 4*(lane>>4)+reg
                op[row * 64 + c * 16 + i] = lrelu(acc[c][r]);
            }
        }
    }
}

extern "C" void kernel_launch(void* const* d_in, const int* in_sizes, int n_in,
                              void* d_out, int out_size, void* d_ws, size_t ws_size,
                              hipStream_t stream) {
    const float* x      = (const float*)d_in[0];
    // d_in[1]=rel_rec, d_in[2]=rel_send: one-hot edge matrices, replaced by index math
    const float* W_sp   = (const float*)d_in[3];
    const float* b_sp   = (const float*)d_in[4];
    const float* W_node = (const float*)d_in[5];
    const float* b_node = (const float*)d_in[6];
    const float* W_att  = (const float*)d_in[7];
    const float* b_att  = (const float*)d_in[8];
    float* out = (float*)d_out;

    dim3 grid(BB * TM1);
    dim3 block(256);
    hipLaunchKernelGGL(gat_kernel, grid, block, 0, stream,
                       x, W_sp, b_sp, W_node, b_node, W_att, b_att, out);
}

// Round 6
// 14.692 us; speedup vs baseline: 1.1947x; 1.1947x over previous
//
#include <hip/hip_runtime.h>
#include <math.h>

#define BB 8
#define TM1 127

typedef _Float16 f16x4 __attribute__((ext_vector_type(4)));
typedef float f32x4 __attribute__((ext_vector_type(4)));
typedef unsigned int u32x4 __attribute__((ext_vector_type(4)));

__device__ __forceinline__ float lrelu(float v) { return v > 0.0f ? v : 0.01f * v; }

__global__ __launch_bounds__(256, 4) void gat_kernel(
    const float* __restrict__ x,       // (8,64,128,8)
    const float* __restrict__ W_sp,    // (24,64)
    const float* __restrict__ b_sp,    // (64)
    const float* __restrict__ W_node,  // (8,64)
    const float* __restrict__ b_node,  // (64)
    const float* __restrict__ W_att,   // (64,1)
    const float* __restrict__ b_att,   // (1)
    float* __restrict__ out)           // (8,127,64,64)
{
    const int bt = blockIdx.x;
    const int b = bt / TM1;
    const int t = bt - b * TM1;
    const int tid = threadIdx.x;
    const int lane = tid & 63;
    const int wid = tid >> 6;

    __shared__ __align__(16) unsigned short Nh[64][72];   // f16 ne, [d][f], 144B rows
    __shared__ __align__(16) float u_sh[64];
    __shared__ __align__(16) float w_sh[64];
    __shared__ __align__(16) float red[20];               // p[0..7], q[0..7], c0, c1

    const float wa = W_att[lane];
    float Wn[8];
#pragma unroll
    for (int k = 0; k < 8; ++k) Wn[k] = W_node[k * 64 + lane];
    const float bnode_d = b_node[lane];
    const float batt = b_att[0];

    // issue wave0's per-lane x gather EARLY (t and t+1 rows are 16 contiguous floats)
    f32x4 xa0, xa1, xd0, xd1;
    if (wid == 0) {
        const float* xr = x + ((b * 64 + lane) * 128 + t) * 8;
        xa0 = *(const f32x4*)(xr);
        xa1 = *(const f32x4*)(xr + 4);
        xd0 = *(const f32x4*)(xr + 8);
        xd1 = *(const f32x4*)(xr + 12);
    }

    // ---- reductions: wave w handles values 5w..5w+4 (18 total), 30 shuffles/wave ----
    {
        const int v0 = wid * 5;
        float pr[5];
#pragma unroll
        for (int j = 0; j < 5; ++j) {
            int v = v0 + j;
            float val;
            if (v < 8)       val = W_node[v * 64 + lane] * wa;            // p[v]
            else if (v < 16) val = (W_sp[v * 64 + lane] + W_sp[(v + 8) * 64 + lane]) * wa; // q[v-8]
            else if (v == 16) val = b_sp[lane] * wa;                      // c0
            else             val = bnode_d * wa;                          // c1 (v>=17)
            pr[j] = val;
        }
#pragma unroll
        for (int j = 0; j < 5; ++j) {
            float vv = pr[j];
#pragma unroll
            for (int off = 1; off < 64; off <<= 1) vv += __shfl_xor(vv, off, 64);
            pr[j] = vv;
        }
        if (lane == 0) {
#pragma unroll
            for (int j = 0; j < 5; ++j) {
                int v = v0 + j;
                if (v < 18) red[v] = pr[j];
            }
        }
    }

    // ---- ne[f][d] via wave-uniform s_load rows (no LDS reads) ----
    {
        unsigned int hw[8];
#pragma unroll
        for (int p = 0; p < 8; ++p) {
            int f0 = wid * 16 + 2 * p;
            int off = ((b * 64 + f0) * 128 + t) * 8;
            off = __builtin_amdgcn_readfirstlane(off);   // SGPR pointer -> s_load
            const float* r0 = x + off;
            const float* r1 = r0 + 1024;                 // row f0+1 (128*8)
            float acc0 = bnode_d, acc1 = bnode_d;
#pragma unroll
            for (int e = 0; e < 8; ++e) {
                acc0 += r0[e] * Wn[e];
                acc1 += r1[e] * Wn[e];
            }
            _Float16 h0 = (_Float16)acc0, h1 = (_Float16)acc1;
            hw[p] = (unsigned int)__builtin_bit_cast(unsigned short, h0) |
                    ((unsigned int)__builtin_bit_cast(unsigned short, h1) << 16);
        }
        u32x4 qa = {hw[0], hw[1], hw[2], hw[3]};
        u32x4 qb = {hw[4], hw[5], hw[6], hw[7]};
        *(u32x4*)&Nh[lane][wid * 16]     = qa;
        *(u32x4*)&Nh[lane][wid * 16 + 8] = qb;
    }
    __syncthreads();   // B1: red[] published (Nh also done)

    // ---- u[n], w[n] (wave 0; x already in registers) ----
    if (wid == 0) {
        float su = 0.f, sw = 0.f;
#pragma unroll
        for (int e = 0; e < 4; ++e) {
            su += xa0[e] * red[e] + xa1[e] * red[4 + e];
            sw += (xd0[e] - xa0[e]) * red[8 + e] + (xd1[e] - xa1[e]) * red[12 + e];
        }
        u_sh[lane] = su + red[17];
        w_sh[lane] = sw + red[16];
    }
    __syncthreads();   // B2

    // ---- phase C: S + softmax in registers (A-frag layout), MFMA, store ----
    {
        const int i = lane & 15;
        const int g4 = (lane >> 4) * 4;
        const int n = wid * 16 + i;          // this lane's attention row
        const float un = u_sh[n];

        float a[16];
#pragma unroll
        for (int s4 = 0; s4 < 4; ++s4) {
            f32x4 uf = *(const f32x4*)&u_sh[s4 * 16 + g4];
            f32x4 wf = *(const f32x4*)&w_sh[s4 * 16 + g4];
#pragma unroll
            for (int e = 0; e < 4; ++e) {
                int f = s4 * 16 + g4 + e;
                float v = lrelu(un + uf[e] + wf[e] + batt);
                a[s4 * 4 + e] = (f == n) ? 0.0f : v;
            }
        }
        // row softmax: row n lives in lanes {i, i+16, i+32, i+48}
        float m = a[0];
#pragma unroll
        for (int j = 1; j < 16; ++j) m = fmaxf(m, a[j]);
        m = fmaxf(m, __shfl_xor(m, 16, 64));
        m = fmaxf(m, __shfl_xor(m, 32, 64));
        float s = 0.f;
#pragma unroll
        for (int j = 0; j < 16; ++j) {
            float e = __expf(a[j] - m);
            a[j] = e;
            s += e;
        }
        s += __shfl_xor(s, 16, 64);
        s += __shfl_xor(s, 32, 64);
        const float inv = 1.0f / s;

        f16x4 Ah[4];
#pragma unroll
        for (int s4 = 0; s4 < 4; ++s4)
#pragma unroll
            for (int e = 0; e < 4; ++e)
                Ah[s4][e] = (_Float16)(a[s4 * 4 + e] * inv);

        f32x4 acc[4];
#pragma unroll
        for (int c = 0; c < 4; ++c) acc[c] = (f32x4){0.f, 0.f, 0.f, 0.f};

#pragma unroll
        for (int c = 0; c < 4; ++c) {
            const int col = c * 16 + i;
#pragma unroll
            for (int s4 = 0; s4 < 4; ++s4) {
                f16x4 bh = *(const f16x4*)&Nh[col][s4 * 16 + g4];
                acc[c] = __builtin_amdgcn_mfma_f32_16x16x16f16(Ah[s4], bh, acc[c], 0, 0, 0);
            }
        }

        float* op = out + ((long)(b * TM1 + t) << 12);
#pragma unroll
        for (int c = 0; c < 4; ++c) {
#pragma unroll
            for (int r = 0; r < 4; ++r) {
                int row = wid * 16 + g4 + r;     // C/D: row = 4*(lane>>4)+reg
                op[row * 64 + c * 16 + i] = lrelu(acc[c][r]);
            }
        }
    }
}

extern "C" void kernel_launch(void* const* d_in, const int* in_sizes, int n_in,
                              void* d_out, int out_size, void* d_ws, size_t ws_size,
                              hipStream_t stream) {
    const float* x      = (const float*)d_in[0];
    // d_in[1]=rel_rec, d_in[2]=rel_send: one-hot edge matrices, replaced by index math
    const float* W_sp   = (const float*)d_in[3];
    const float* b_sp   = (const float*)d_in[4];
    const float* W_node = (const float*)d_in[5];
    const float* b_node = (const float*)d_in[6];
    const float* W_att  = (const float*)d_in[7];
    const float* b_att  = (const float*)d_in[8];
    float* out = (float*)d_out;

    dim3 grid(BB * TM1);
    dim3 block(256);
    hipLaunchKernelGGL(gat_kernel, grid, block, 0, stream,
                       x, W_sp, b_sp, W_node, b_node, W_att, b_att, out);
}